// Round 1
// baseline (2996.309 us; speedup 1.0000x reference)
//
#include <hip/hip_runtime.h>

typedef __bf16 bf16x8 __attribute__((ext_vector_type(8)));
typedef float  f32x4  __attribute__((ext_vector_type(4)));

union U4 { uint4 u; bf16x8 v; };

__device__ __forceinline__ bf16x8 ld_frag(const void* p) {
    U4 t; t.u = *(const uint4*)p; return t.v;
}

__device__ __forceinline__ float sigf(float x) {
    return __builtin_amdgcn_rcpf(1.f + __expf(-x));
}
__device__ __forceinline__ float tanhf_fast(float x) {
    return 1.f - 2.f * __builtin_amdgcn_rcpf(1.f + __expf(2.f * x));
}

#define MFMA(A,B,C) C = __builtin_amdgcn_mfma_f32_16x16x32_bf16(A, B, C, 0, 0, 0)

// ---------------------------------------------------------------------------
// Pack [Wx (16 rows, pad to 32); Uh (256); Uh2 (256)] -> K=544 rows x 768 cols
// per direction, as B-fragments for mfma_f32_16x16x32_bf16:
// pack[a][kt(17)][nt(48)][lane(64)] = 8 bf16 : B[kt*32 + (lane>>4)*8 + j][nt*16 + (lane&15)]
// ---------------------------------------------------------------------------
__global__ void pack_kernel(const float* __restrict__ Wx, const float* __restrict__ Uh,
                            const float* __restrict__ Uh2, uint4* __restrict__ packW) {
    int tid = blockIdx.x * 256 + threadIdx.x;   // exactly 4*17*48*64 = 208896 threads
    int lane = tid & 63;
    int nt   = (tid >> 6) % 48;
    int kt   = ((tid >> 6) / 48) % 17;
    int a    = (tid >> 6) / (48 * 17);
    int col  = nt * 16 + (lane & 15);
    int kbase = kt * 32 + (lane >> 4) * 8;
    U4 u;
#pragma unroll
    for (int jj = 0; jj < 8; jj++) {
        int k = kbase + jj;
        float v;
        if (k < 16)       v = Wx[(a * 16 + k) * 768 + col];
        else if (k < 32)  v = 0.f;
        else if (k < 288) v = Uh[(a * 256 + (k - 32)) * 768 + col];
        else              v = Uh2[(a * 256 + (k - 288)) * 768 + col];
        u.v[jj] = (__bf16)v;
    }
    packW[tid] = u.u;
}

// ---------------------------------------------------------------------------
// Wavefront kernel: one block = one cell (a,i,j) x one 32-col gate group g.
// Block = 256 thr (4 waves); wave w handles batch rows [64w, 64w+64).
// acc tiles per (mt): 0,1=r  2,3=z  4,5=n_h (Uh/Uh2 part)  6,7=n_x (Wx part)
// hbuf layout: [parity 2][a 4][j 29][b 256][c 256] bf16
// ---------------------------------------------------------------------------
__global__ __launch_bounds__(256, 2) void wf_kernel(
    const float* __restrict__ x, const uint4* __restrict__ packW,
    const float* __restrict__ bias, __bf16* __restrict__ hbuf,
    int d, int4 ends)
{
    int bx = blockIdx.x;
    int a, base;
    if (bx < ends.x)      { a = 0; base = 0; }
    else if (bx < ends.y) { a = 1; base = ends.x; }
    else if (bx < ends.z) { a = 2; base = ends.y; }
    else                  { a = 3; base = ends.z; }
    int t    = bx - base;
    int cell = t >> 3;
    int g    = t & 7;
    int Nx   = 29 - ((a >> 1) & 1);
    int istart = d - (Nx - 1); if (istart < 0) istart = 0;
    int i = istart + cell;
    int j = d - i;
    int y0 = (a & 1) ? (27 - i) : i;
    int x0 = (a & 2) ? (27 - j) : j;
    bool hasA = (i > 0);
    bool hasL = (j > 0);

    int tid = threadIdx.x;
    int w    = tid >> 6;
    int lane = tid & 63;
    int q    = lane >> 4;
    int l16  = lane & 15;

    int pprev = (d - 1) & 1;
    int pcur  = d & 1;
    const __bf16* hA = hbuf + ((size_t)(pprev * 4 + a) * 29 + j) * 65536;
    const __bf16* hL = hbuf + ((size_t)(pprev * 4 + a) * 29 + (j - 1)) * 65536;

    f32x4 acc[4][8];
#pragma unroll
    for (int mt = 0; mt < 4; mt++)
#pragma unroll
        for (int tt = 0; tt < 8; tt++)
#pragma unroll
            for (int e = 0; e < 4; e++) acc[mt][tt][e] = 0.f;

    int nt0 = 2 * g, nt1 = 2 * g + 1;
    // ---- k-step 0: x-part (K=16 padded to 32) ----
    {
        const uint4* bp = packW + (size_t)(a * 17 + 0) * 48 * 64 + lane;
        bf16x8 bf0 = ld_frag(bp + nt0 * 64);
        bf16x8 bf1 = ld_frag(bp + nt1 * 64);
        bf16x8 bf2 = ld_frag(bp + (16 + nt0) * 64);
        bf16x8 bf3 = ld_frag(bp + (16 + nt1) * 64);
        bf16x8 bf4 = ld_frag(bp + (32 + nt0) * 64);
        bf16x8 bf5 = ld_frag(bp + (32 + nt1) * 64);
#pragma unroll
        for (int mt = 0; mt < 4; mt++) {
            bf16x8 af;
            if (q < 2) {
                int m = w * 64 + mt * 16 + l16;
                const float* xp = x + m * 1024 + (y0 + 2 * q) * 32 + x0;
#pragma unroll
                for (int jj = 0; jj < 8; jj++)
                    af[jj] = (__bf16)xp[(jj >> 2) * 32 + (jj & 3)];
            } else {
#pragma unroll
                for (int jj = 0; jj < 8; jj++) af[jj] = (__bf16)0.f;
            }
            MFMA(af, bf0, acc[mt][0]); MFMA(af, bf1, acc[mt][1]);
            MFMA(af, bf2, acc[mt][2]); MFMA(af, bf3, acc[mt][3]);
            MFMA(af, bf4, acc[mt][6]); MFMA(af, bf5, acc[mt][7]);
        }
    }
    // ---- k-steps 1..8: h_above @ Uh ----
    if (hasA) {
#pragma unroll 2
        for (int kt = 1; kt <= 8; kt++) {
            const uint4* bp = packW + (size_t)(a * 17 + kt) * 48 * 64 + lane;
            bf16x8 bf0 = ld_frag(bp + nt0 * 64);
            bf16x8 bf1 = ld_frag(bp + nt1 * 64);
            bf16x8 bf2 = ld_frag(bp + (16 + nt0) * 64);
            bf16x8 bf3 = ld_frag(bp + (16 + nt1) * 64);
            bf16x8 bf4 = ld_frag(bp + (32 + nt0) * 64);
            bf16x8 bf5 = ld_frag(bp + (32 + nt1) * 64);
            int khid = (kt - 1) * 32 + q * 8;
#pragma unroll
            for (int mt = 0; mt < 4; mt++) {
                int m = w * 64 + mt * 16 + l16;
                bf16x8 af = ld_frag(hA + m * 256 + khid);
                MFMA(af, bf0, acc[mt][0]); MFMA(af, bf1, acc[mt][1]);
                MFMA(af, bf2, acc[mt][2]); MFMA(af, bf3, acc[mt][3]);
                MFMA(af, bf4, acc[mt][4]); MFMA(af, bf5, acc[mt][5]);
            }
        }
    }
    // ---- k-steps 9..16: h_left @ Uh2 ----
    if (hasL) {
#pragma unroll 2
        for (int kt = 9; kt <= 16; kt++) {
            const uint4* bp = packW + (size_t)(a * 17 + kt) * 48 * 64 + lane;
            bf16x8 bf0 = ld_frag(bp + nt0 * 64);
            bf16x8 bf1 = ld_frag(bp + nt1 * 64);
            bf16x8 bf2 = ld_frag(bp + (16 + nt0) * 64);
            bf16x8 bf3 = ld_frag(bp + (16 + nt1) * 64);
            bf16x8 bf4 = ld_frag(bp + (32 + nt0) * 64);
            bf16x8 bf5 = ld_frag(bp + (32 + nt1) * 64);
            int khid = (kt - 9) * 32 + q * 8;
#pragma unroll
            for (int mt = 0; mt < 4; mt++) {
                int m = w * 64 + mt * 16 + l16;
                bf16x8 af = ld_frag(hL + m * 256 + khid);
                MFMA(af, bf0, acc[mt][0]); MFMA(af, bf1, acc[mt][1]);
                MFMA(af, bf2, acc[mt][2]); MFMA(af, bf3, acc[mt][3]);
                MFMA(af, bf4, acc[mt][4]); MFMA(af, bf5, acc[mt][5]);
            }
        }
    }
    // ---- epilogue: gates + state update ----
    const float* ba = bias + a * 768;
    __bf16* hout = hbuf + ((size_t)(pcur * 4 + a) * 29 + j) * 65536;
#pragma unroll
    for (int s = 0; s < 2; s++) {
        int c = g * 32 + s * 16 + l16;
        float bR = ba[c], bZ = ba[256 + c], bN = ba[512 + c];
#pragma unroll
        for (int mt = 0; mt < 4; mt++) {
#pragma unroll
            for (int r2 = 0; r2 < 4; r2++) {
                int m = w * 64 + mt * 16 + q * 4 + r2;
                float r = sigf(acc[mt][0 + s][r2] + bR);
                float z = sigf(acc[mt][2 + s][r2] + bZ);
                float n = tanhf_fast(acc[mt][6 + s][r2] + bN + r * acc[mt][4 + s][r2]);
                float hsum = 0.f;
                if (hasA) hsum += (float)hA[m * 256 + c];
                if (hasL) hsum += (float)hL[m * 256 + c];
                float hn = (1.f - z) * n + 0.5f * z * hsum;
                hout[m * 256 + c] = (__bf16)hn;
            }
        }
    }
}

// ---------------------------------------------------------------------------
// Output: logits = hcat @ W_out + b_out, then log_softmax. One wave per batch.
// ---------------------------------------------------------------------------
__global__ __launch_bounds__(64) void out_kernel(const __bf16* __restrict__ hbuf,
    const float* __restrict__ Wout, const float* __restrict__ bout,
    float* __restrict__ out)
{
    int b = blockIdx.x;
    int t = threadIdx.x;
    float accv[10];
#pragma unroll
    for (int o = 0; o < 10; o++) accv[o] = 0.f;
    for (int it = 0; it < 16; ++it) {
        int k = it * 64 + t;
        int a = k >> 8, c = k & 255;
        int Ny = 29 - (a & 1), Nx = 29 - ((a >> 1) & 1);
        int p  = (Ny + Nx - 2) & 1;
        int jf = Nx - 1;
        float h = (float)hbuf[((size_t)(p * 4 + a) * 29 + jf) * 65536 + (size_t)b * 256 + c];
        const float* wr = Wout + k * 10;
#pragma unroll
        for (int o = 0; o < 10; o++) accv[o] += h * wr[o];
    }
#pragma unroll
    for (int off = 32; off > 0; off >>= 1)
#pragma unroll
        for (int o = 0; o < 10; o++) accv[o] += __shfl_down(accv[o], off, 64);
    if (t == 0) {
        float l[10];
#pragma unroll
        for (int o = 0; o < 10; o++) l[o] = accv[o] + bout[o];
        float mx = l[0];
#pragma unroll
        for (int o = 1; o < 10; o++) mx = fmaxf(mx, l[o]);
        float se = 0.f;
#pragma unroll
        for (int o = 0; o < 10; o++) se += __expf(l[o] - mx);
        float lse = mx + __logf(se);
#pragma unroll
        for (int o = 0; o < 10; o++) out[b * 10 + o] = l[o] - lse;
    }
}

extern "C" void kernel_launch(void* const* d_in, const int* in_sizes, int n_in,
                              void* d_out, int out_size, void* d_ws, size_t ws_size,
                              hipStream_t stream) {
    const float* x    = (const float*)d_in[0];
    const float* Wx   = (const float*)d_in[1];
    const float* Uh   = (const float*)d_in[2];
    const float* Uh2  = (const float*)d_in[3];
    const float* b    = (const float*)d_in[4];
    const float* Wout = (const float*)d_in[5];
    const float* bout = (const float*)d_in[6];
    float* out = (float*)d_out;

    char* ws = (char*)d_ws;
    uint4*  packW = (uint4*)ws;                          // 208896 * 16B = 3,342,336 B
    __bf16* hbuf  = (__bf16*)(ws + 3407872);             // 2*4*29*65536*2 = 30,408,704 B

    pack_kernel<<<816, 256, 0, stream>>>(Wx, Uh, Uh2, packW);

    for (int d = 0; d < 57; ++d) {
        int ends[4]; int total = 0;
        for (int a = 0; a < 4; a++) {
            int Ny = 29 - (a & 1), Nx = 29 - ((a >> 1) & 1);
            int cnt = 0;
            if (d <= Ny + Nx - 2) {
                int is = d - (Nx - 1); if (is < 0) is = 0;
                int ie = (d < Ny - 1) ? d : Ny - 1;
                cnt = ie - is + 1;
            }
            total += cnt * 8;
            ends[a] = total;
        }
        wf_kernel<<<total, 256, 0, stream>>>(x, packW, b, hbuf, d,
                                             make_int4(ends[0], ends[1], ends[2], ends[3]));
    }
    out_kernel<<<256, 64, 0, stream>>>(hbuf, Wout, bout, out);
}

// Round 2
// 2696.895 us; speedup vs baseline: 1.1110x; 1.1110x over previous
//
#include <hip/hip_runtime.h>

typedef __bf16 bf16x8 __attribute__((ext_vector_type(8)));
typedef float  f32x4  __attribute__((ext_vector_type(4)));

union U4 { uint4 u; bf16x8 v; };

__device__ __forceinline__ bf16x8 ld_frag(const void* p) {
    U4 t; t.u = *(const uint4*)p; return t.v;
}

__device__ __forceinline__ float sigf(float x) {
    return __builtin_amdgcn_rcpf(1.f + __expf(-x));
}
__device__ __forceinline__ float tanhf_fast(float x) {
    return 1.f - 2.f * __builtin_amdgcn_rcpf(1.f + __expf(2.f * x));
}

#define MFMA(A,B,C) C = __builtin_amdgcn_mfma_f32_16x16x32_bf16(A, B, C, 0, 0, 0)

// ---------------------------------------------------------------------------
// Pack [Wx (16 rows, pad to 32); Uh (256); Uh2 (256)] -> K=544 rows x 768 cols
// per direction, as B-fragments for mfma_f32_16x16x32_bf16:
// pack[a][kt(17)][nt(48)][lane(64)] = 8 bf16 : B[kt*32+(lane>>4)*8+j][nt*16+(lane&15)]
// ---------------------------------------------------------------------------
__global__ void pack_kernel(const float* __restrict__ Wx, const float* __restrict__ Uh,
                            const float* __restrict__ Uh2, uint4* __restrict__ packW) {
    int tid = blockIdx.x * 256 + threadIdx.x;   // exactly 4*17*48*64 = 208896 threads
    int lane = tid & 63;
    int nt   = (tid >> 6) % 48;
    int kt   = ((tid >> 6) / 48) % 17;
    int a    = (tid >> 6) / (48 * 17);
    int col  = nt * 16 + (lane & 15);
    int kbase = kt * 32 + (lane >> 4) * 8;
    U4 u;
#pragma unroll
    for (int jj = 0; jj < 8; jj++) {
        int k = kbase + jj;
        float v;
        if (k < 16)       v = Wx[(a * 16 + k) * 768 + col];
        else if (k < 32)  v = 0.f;
        else if (k < 288) v = Uh[(a * 256 + (k - 32)) * 768 + col];
        else              v = Uh2[(a * 256 + (k - 288)) * 768 + col];
        u.v[jj] = (__bf16)v;
    }
    packW[tid] = u.u;
}

// ---------------------------------------------------------------------------
// Pack x patches into A-fragment layout:
// xpack[a][i(29)][j(29)][m(256)][q(2)] = uint4 (8 bf16): x-patch element k=q*8+jj
// ---------------------------------------------------------------------------
__global__ void xpack_kernel(const float* __restrict__ x, uint4* __restrict__ xp) {
    int tid = blockIdx.x * 256 + threadIdx.x;   // 4*29*29*256*2 = 1,722,368 threads
    int q = tid & 1;
    int m = (tid >> 1) & 255;
    int rem = tid >> 9;                          // a*841 + i*29 + j
    int j = rem % 29;
    int t2 = rem / 29;
    int i = t2 % 29;
    int a = t2 / 29;
    int Ny = 29 - (a & 1), Nx = 29 - ((a >> 1) & 1);
    U4 u;
    if (i < Ny && j < Nx) {
        int y0 = (a & 1) ? (27 - i) : i;
        int x0 = (a & 2) ? (27 - j) : j;
        const float* px = x + m * 1024 + y0 * 32 + x0;
#pragma unroll
        for (int jj = 0; jj < 8; jj++) {
            int k = q * 8 + jj;
            u.v[jj] = (__bf16)px[(k >> 2) * 32 + (k & 3)];
        }
    } else {
#pragma unroll
        for (int jj = 0; jj < 8; jj++) u.v[jj] = (__bf16)0.f;
    }
    xp[tid] = u.u;
}

// ---------------------------------------------------------------------------
// Wavefront kernel: one block = one cell (a,i,j) x one 32-col gate group g.
// Block index swizzle pins work to XCDs (xcd ~ blockIdx%8):
//   bx = 64*(cell>>1) + 8*g + (2a + (cell&1))
// -> dir a lives on XCD pair {2a,2a+1}; all 8 g-blocks of a cell share one XCD.
// Block = 256 thr (4 waves); wave w handles batch rows [64w, 64w+64).
// acc tiles per (mt): 0,1=r  2,3=z  4,5=n_h (Uh/Uh2 part)  6,7=n_x (Wx part)
// hbuf layout: [parity 2][a 4][j 29][b 256][c 256] bf16
// ---------------------------------------------------------------------------
__global__ __launch_bounds__(256, 2) void wf_kernel(
    const float* __restrict__ x, const uint4* __restrict__ xpack,
    const uint4* __restrict__ packW, const float* __restrict__ bias,
    __bf16* __restrict__ hbuf, int d, int4 cnt4)
{
    int bx   = blockIdx.x;
    int r    = bx & 7;
    int a    = r >> 1;
    int par  = r & 1;
    int g    = (bx >> 3) & 7;
    int cell = ((bx >> 6) << 1) + par;
    int cnt_a = (a == 0) ? cnt4.x : (a == 1) ? cnt4.y : (a == 2) ? cnt4.z : cnt4.w;
    if (cell >= cnt_a) return;

    int Nx   = 29 - ((a >> 1) & 1);
    int istart = d - (Nx - 1); if (istart < 0) istart = 0;
    int i = istart + cell;
    int j = d - i;
    bool hasA = (i > 0);
    bool hasL = (j > 0);

    int tid = threadIdx.x;
    int w    = tid >> 6;
    int lane = tid & 63;
    int q    = lane >> 4;
    int l16  = lane & 15;

    int pprev = (d - 1) & 1;
    int pcur  = d & 1;
    const __bf16* hA = hbuf + ((size_t)(pprev * 4 + a) * 29 + j) * 65536;
    const __bf16* hL = hbuf + ((size_t)(pprev * 4 + a) * 29 + (j - 1)) * 65536;

    f32x4 acc[4][8];
#pragma unroll
    for (int mt = 0; mt < 4; mt++)
#pragma unroll
        for (int tt = 0; tt < 8; tt++)
#pragma unroll
            for (int e = 0; e < 4; e++) acc[mt][tt][e] = 0.f;

    int nt0 = 2 * g, nt1 = 2 * g + 1;
    // ---- k-step 0: x-part (K=16 padded to 32) ----
    {
        const uint4* bp = packW + (size_t)(a * 17 + 0) * 48 * 64 + lane;
        bf16x8 bf0 = ld_frag(bp + nt0 * 64);
        bf16x8 bf1 = ld_frag(bp + nt1 * 64);
        bf16x8 bf2 = ld_frag(bp + (16 + nt0) * 64);
        bf16x8 bf3 = ld_frag(bp + (16 + nt1) * 64);
        bf16x8 bf4 = ld_frag(bp + (32 + nt0) * 64);
        bf16x8 bf5 = ld_frag(bp + (32 + nt1) * 64);
        if (xpack) {
            const uint4* xpc = xpack + ((size_t)((a * 29 + i) * 29 + j) * 256) * 2 + q;
#pragma unroll
            for (int mt = 0; mt < 4; mt++) {
                bf16x8 af;
                if (q < 2) {
                    af = ld_frag(xpc + (w * 64 + mt * 16 + l16) * 2);
                } else {
#pragma unroll
                    for (int jj = 0; jj < 8; jj++) af[jj] = (__bf16)0.f;
                }
                MFMA(af, bf0, acc[mt][0]); MFMA(af, bf1, acc[mt][1]);
                MFMA(af, bf2, acc[mt][2]); MFMA(af, bf3, acc[mt][3]);
                MFMA(af, bf4, acc[mt][6]); MFMA(af, bf5, acc[mt][7]);
            }
        } else {
            int y0 = (a & 1) ? (27 - i) : i;
            int x0 = (a & 2) ? (27 - j) : j;
#pragma unroll
            for (int mt = 0; mt < 4; mt++) {
                bf16x8 af;
                if (q < 2) {
                    int m = w * 64 + mt * 16 + l16;
                    const float* xp = x + m * 1024 + (y0 + 2 * q) * 32 + x0;
#pragma unroll
                    for (int jj = 0; jj < 8; jj++)
                        af[jj] = (__bf16)xp[(jj >> 2) * 32 + (jj & 3)];
                } else {
#pragma unroll
                    for (int jj = 0; jj < 8; jj++) af[jj] = (__bf16)0.f;
                }
                MFMA(af, bf0, acc[mt][0]); MFMA(af, bf1, acc[mt][1]);
                MFMA(af, bf2, acc[mt][2]); MFMA(af, bf3, acc[mt][3]);
                MFMA(af, bf4, acc[mt][6]); MFMA(af, bf5, acc[mt][7]);
            }
        }
    }
    // ---- k-steps 1..8: h_above @ Uh ----
    if (hasA) {
#pragma unroll 2
        for (int kt = 1; kt <= 8; kt++) {
            const uint4* bp = packW + (size_t)(a * 17 + kt) * 48 * 64 + lane;
            bf16x8 bf0 = ld_frag(bp + nt0 * 64);
            bf16x8 bf1 = ld_frag(bp + nt1 * 64);
            bf16x8 bf2 = ld_frag(bp + (16 + nt0) * 64);
            bf16x8 bf3 = ld_frag(bp + (16 + nt1) * 64);
            bf16x8 bf4 = ld_frag(bp + (32 + nt0) * 64);
            bf16x8 bf5 = ld_frag(bp + (32 + nt1) * 64);
            int khid = (kt - 1) * 32 + q * 8;
#pragma unroll
            for (int mt = 0; mt < 4; mt++) {
                int m = w * 64 + mt * 16 + l16;
                bf16x8 af = ld_frag(hA + m * 256 + khid);
                MFMA(af, bf0, acc[mt][0]); MFMA(af, bf1, acc[mt][1]);
                MFMA(af, bf2, acc[mt][2]); MFMA(af, bf3, acc[mt][3]);
                MFMA(af, bf4, acc[mt][4]); MFMA(af, bf5, acc[mt][5]);
            }
        }
    }
    // ---- k-steps 9..16: h_left @ Uh2 ----
    if (hasL) {
#pragma unroll 2
        for (int kt = 9; kt <= 16; kt++) {
            const uint4* bp = packW + (size_t)(a * 17 + kt) * 48 * 64 + lane;
            bf16x8 bf0 = ld_frag(bp + nt0 * 64);
            bf16x8 bf1 = ld_frag(bp + nt1 * 64);
            bf16x8 bf2 = ld_frag(bp + (16 + nt0) * 64);
            bf16x8 bf3 = ld_frag(bp + (16 + nt1) * 64);
            bf16x8 bf4 = ld_frag(bp + (32 + nt0) * 64);
            bf16x8 bf5 = ld_frag(bp + (32 + nt1) * 64);
            int khid = (kt - 9) * 32 + q * 8;
#pragma unroll
            for (int mt = 0; mt < 4; mt++) {
                int m = w * 64 + mt * 16 + l16;
                bf16x8 af = ld_frag(hL + m * 256 + khid);
                MFMA(af, bf0, acc[mt][0]); MFMA(af, bf1, acc[mt][1]);
                MFMA(af, bf2, acc[mt][2]); MFMA(af, bf3, acc[mt][3]);
                MFMA(af, bf4, acc[mt][4]); MFMA(af, bf5, acc[mt][5]);
            }
        }
    }
    // ---- epilogue: gates + state update ----
    const float* ba = bias + a * 768;
    __bf16* hout = hbuf + ((size_t)(pcur * 4 + a) * 29 + j) * 65536;
#pragma unroll
    for (int s = 0; s < 2; s++) {
        int c = g * 32 + s * 16 + l16;
        float bR = ba[c], bZ = ba[256 + c], bN = ba[512 + c];
#pragma unroll
        for (int mt = 0; mt < 4; mt++) {
#pragma unroll
            for (int r2 = 0; r2 < 4; r2++) {
                int m = w * 64 + mt * 16 + q * 4 + r2;
                float rr = sigf(acc[mt][0 + s][r2] + bR);
                float zz = sigf(acc[mt][2 + s][r2] + bZ);
                float nn = tanhf_fast(acc[mt][6 + s][r2] + bN + rr * acc[mt][4 + s][r2]);
                float hsum = 0.f;
                if (hasA) hsum += (float)hA[m * 256 + c];
                if (hasL) hsum += (float)hL[m * 256 + c];
                float hn = (1.f - zz) * nn + 0.5f * zz * hsum;
                hout[m * 256 + c] = (__bf16)hn;
            }
        }
    }
}

// ---------------------------------------------------------------------------
// Output: logits = hcat @ W_out + b_out, then log_softmax. One wave per batch.
// ---------------------------------------------------------------------------
__global__ __launch_bounds__(64) void out_kernel(const __bf16* __restrict__ hbuf,
    const float* __restrict__ Wout, const float* __restrict__ bout,
    float* __restrict__ out)
{
    int b = blockIdx.x;
    int t = threadIdx.x;
    float accv[10];
#pragma unroll
    for (int o = 0; o < 10; o++) accv[o] = 0.f;
    for (int it = 0; it < 16; ++it) {
        int k = it * 64 + t;
        int a = k >> 8, c = k & 255;
        int Ny = 29 - (a & 1), Nx = 29 - ((a >> 1) & 1);
        int p  = (Ny + Nx - 2) & 1;
        int jf = Nx - 1;
        float h = (float)hbuf[((size_t)(p * 4 + a) * 29 + jf) * 65536 + (size_t)b * 256 + c];
        const float* wr = Wout + k * 10;
#pragma unroll
        for (int o = 0; o < 10; o++) accv[o] += h * wr[o];
    }
#pragma unroll
    for (int off = 32; off > 0; off >>= 1)
#pragma unroll
        for (int o = 0; o < 10; o++) accv[o] += __shfl_down(accv[o], off, 64);
    if (t == 0) {
        float l[10];
#pragma unroll
        for (int o = 0; o < 10; o++) l[o] = accv[o] + bout[o];
        float mx = l[0];
#pragma unroll
        for (int o = 1; o < 10; o++) mx = fmaxf(mx, l[o]);
        float se = 0.f;
#pragma unroll
        for (int o = 0; o < 10; o++) se += __expf(l[o] - mx);
        float lse = mx + __logf(se);
#pragma unroll
        for (int o = 0; o < 10; o++) out[b * 10 + o] = l[o] - lse;
    }
}

extern "C" void kernel_launch(void* const* d_in, const int* in_sizes, int n_in,
                              void* d_out, int out_size, void* d_ws, size_t ws_size,
                              hipStream_t stream) {
    const float* x    = (const float*)d_in[0];
    const float* Wx   = (const float*)d_in[1];
    const float* Uh   = (const float*)d_in[2];
    const float* Uh2  = (const float*)d_in[3];
    const float* b    = (const float*)d_in[4];
    const float* Wout = (const float*)d_in[5];
    const float* bout = (const float*)d_in[6];
    float* out = (float*)d_out;

    char* ws = (char*)d_ws;
    // layout (with xpack): packW @0 (3,342,336B, pad->3,407,872)
    //                      xpack @3,407,872 (27,557,888B, pad-> @31,457,280)
    //                      hbuf  @31,457,280 (30,408,704B) => total 61,865,984
    const size_t XPACK_OFF = 3407872;
    const size_t HBUF_OFF_BIG = 31457280;
    const size_t NEED = HBUF_OFF_BIG + 30408704;
    bool use_xp = (ws_size >= NEED);

    uint4*  packW = (uint4*)ws;
    uint4*  xpack = use_xp ? (uint4*)(ws + XPACK_OFF) : nullptr;
    __bf16* hbuf  = (__bf16*)(ws + (use_xp ? HBUF_OFF_BIG : XPACK_OFF));

    pack_kernel<<<816, 256, 0, stream>>>(Wx, Uh, Uh2, packW);
    if (use_xp)
        xpack_kernel<<<6728, 256, 0, stream>>>(x, xpack);

    for (int d = 0; d < 57; ++d) {
        int cnt[4]; int maxc = 0;
        for (int a = 0; a < 4; a++) {
            int Ny = 29 - (a & 1), Nx = 29 - ((a >> 1) & 1);
            int c = 0;
            if (d <= Ny + Nx - 2) {
                int is = d - (Nx - 1); if (is < 0) is = 0;
                int ie = (d < Ny - 1) ? d : Ny - 1;
                c = ie - is + 1;
            }
            cnt[a] = c;
            if (c > maxc) maxc = c;
        }
        int grid = 64 * ((maxc + 1) >> 1);
        wf_kernel<<<grid, 256, 0, stream>>>(x, xpack, packW, b, hbuf, d,
                                            make_int4(cnt[0], cnt[1], cnt[2], cnt[3]));
    }
    out_kernel<<<256, 64, 0, stream>>>(hbuf, Wout, bout, out);
}

// Round 3
// 1988.291 us; speedup vs baseline: 1.5070x; 1.3564x over previous
//
#include <hip/hip_runtime.h>

typedef __bf16 bf16x8 __attribute__((ext_vector_type(8)));
typedef float  f32x4  __attribute__((ext_vector_type(4)));

union U4 { uint4 u; bf16x8 v; };

__device__ __forceinline__ bf16x8 ld_frag(const void* p) {
    U4 t; t.u = *(const uint4*)p; return t.v;
}
__device__ __forceinline__ bf16x8 zfrag() {
    bf16x8 z;
#pragma unroll
    for (int jj = 0; jj < 8; jj++) z[jj] = (__bf16)0.f;
    return z;
}

__device__ __forceinline__ void gl_lds16(const uint4* g, void* l) {
    __builtin_amdgcn_global_load_lds(
        (const __attribute__((address_space(1))) unsigned int*)g,
        (__attribute__((address_space(3))) unsigned int*)l, 16, 0, 0);
}

__device__ __forceinline__ float sigf(float x) {
    return __builtin_amdgcn_rcpf(1.f + __expf(-x));
}
__device__ __forceinline__ float tanhf_fast(float x) {
    return 1.f - 2.f * __builtin_amdgcn_rcpf(1.f + __expf(2.f * x));
}

#define MFMA(A,B,C) C = __builtin_amdgcn_mfma_f32_16x16x32_bf16(A, B, C, 0, 0, 0)

// ---------------------------------------------------------------------------
// Pack [Wx (16 rows, pad to 32); Uh (256); Uh2 (256)] -> K=544 rows x 768 cols
// per direction, as B-fragments:
// pack[a][kt(17)][nt(48)][lane(64)] = 8 bf16 : B[kt*32+(lane>>4)*8+j][nt*16+(lane&15)]
// ---------------------------------------------------------------------------
__global__ void pack_kernel(const float* __restrict__ Wx, const float* __restrict__ Uh,
                            const float* __restrict__ Uh2, uint4* __restrict__ packW) {
    int tid = blockIdx.x * 256 + threadIdx.x;   // exactly 4*17*48*64 = 208896 threads
    int lane = tid & 63;
    int nt   = (tid >> 6) % 48;
    int kt   = ((tid >> 6) / 48) % 17;
    int a    = (tid >> 6) / (48 * 17);
    int col  = nt * 16 + (lane & 15);
    int kbase = kt * 32 + (lane >> 4) * 8;
    U4 u;
#pragma unroll
    for (int jj = 0; jj < 8; jj++) {
        int k = kbase + jj;
        float v;
        if (k < 16)       v = Wx[(a * 16 + k) * 768 + col];
        else if (k < 32)  v = 0.f;
        else if (k < 288) v = Uh[(a * 256 + (k - 32)) * 768 + col];
        else              v = Uh2[(a * 256 + (k - 288)) * 768 + col];
        u.v[jj] = (__bf16)v;
    }
    packW[tid] = u.u;
}

// ---------------------------------------------------------------------------
// Pack x patches into A-fragment layout:
// xpack[a][i(29)][j(29)][m(256)][q(2)] = uint4 (8 bf16): patch element k=q*8+jj
// ---------------------------------------------------------------------------
__global__ void xpack_kernel(const float* __restrict__ x, uint4* __restrict__ xp) {
    int tid = blockIdx.x * 256 + threadIdx.x;   // 4*29*29*256*2 = 1,722,368 threads
    int q = tid & 1;
    int m = (tid >> 1) & 255;
    int rem = tid >> 9;                          // a*841 + i*29 + j
    int j = rem % 29;
    int t2 = rem / 29;
    int i = t2 % 29;
    int a = t2 / 29;
    int Ny = 29 - (a & 1), Nx = 29 - ((a >> 1) & 1);
    U4 u;
    if (i < Ny && j < Nx) {
        int y0 = (a & 1) ? (27 - i) : i;
        int x0 = (a & 2) ? (27 - j) : j;
        const float* px = x + m * 1024 + y0 * 32 + x0;
#pragma unroll
        for (int jj = 0; jj < 8; jj++) {
            int k = q * 8 + jj;
            u.v[jj] = (__bf16)px[(k >> 2) * 32 + (k & 3)];
        }
    } else {
#pragma unroll
        for (int jj = 0; jj < 8; jj++) u.v[jj] = (__bf16)0.f;
    }
    xp[tid] = u.u;
}

// ---------------------------------------------------------------------------
// Wavefront kernel. Block = one cell (a,i,j) x 32-col gate group g, 4 waves.
// Swizzle: bx = 64*(cell>>1) + 8*g + (2a + (cell&1)) -> cell's 8 g-blocks on 1 XCD.
// B-fragments double-buffered in LDS via global_load_lds; A prefetched 1 stage.
// hbuf layout (k-major per slice): [parity 2][a 4][j 29][kt 8][m 256][c32 32] bf16
//   slice = 65536 elems; frag(kt,m,q) at byte (kt*16384 + m*64 + q*16).
// acc tiles per mt: 0,1=r  2,3=z  4,5=n_h  6,7=n_x
// ---------------------------------------------------------------------------
__global__ __launch_bounds__(256, 2) void wf_kernel(
    const float* __restrict__ x, const uint4* __restrict__ xpack,
    const uint4* __restrict__ packW, const float* __restrict__ bias,
    __bf16* __restrict__ hbuf, int d, int4 cnt4)
{
    __shared__ __align__(16) unsigned char smemB[12288];   // 2 bufs x 6 KB

    int bx   = blockIdx.x;
    int rr   = bx & 7;
    int a    = rr >> 1;
    int par  = rr & 1;
    int g    = (bx >> 3) & 7;
    int cell = ((bx >> 6) << 1) + par;
    int cnt_a = (a == 0) ? cnt4.x : (a == 1) ? cnt4.y : (a == 2) ? cnt4.z : cnt4.w;
    if (cell >= cnt_a) return;

    int Nx   = 29 - ((a >> 1) & 1);
    int istart = d - (Nx - 1); if (istart < 0) istart = 0;
    int i = istart + cell;
    int j = d - i;
    bool hasA = (i > 0);
    bool hasL = (j > 0);

    int tid  = threadIdx.x;
    int w    = tid >> 6;
    int lane = tid & 63;
    int q    = lane >> 4;
    int l16  = lane & 15;

    int pprev = (d - 1) & 1;
    int pcur  = d & 1;
    const char* hAB = (const char*)(hbuf + ((size_t)(pprev * 4 + a) * 29 + j) * 65536);
    const char* hLB = (const char*)(hbuf + ((size_t)(pprev * 4 + a) * 29 + (j - 1)) * 65536);

    f32x4 acc[4][8];
#pragma unroll
    for (int mt = 0; mt < 4; mt++)
#pragma unroll
        for (int tt = 0; tt < 8; tt++)
#pragma unroll
            for (int e = 0; e < 4; e++) acc[mt][tt][e] = 0.f;

    // issue the 6 B chunks for stage kt into buf[kt&1]; wave w takes chunk w (+ 4+w if w<2)
    auto issueB = [&](int kt) {
        unsigned char* dst = smemB + (kt & 1) * 6144;
        const uint4* srcbase = packW + (size_t)(a * 17 + kt) * 48 * 64;
        {
            int c  = w;
            int nt = (c >> 1) * 16 + 2 * g + (c & 1);
            gl_lds16(srcbase + nt * 64 + lane, dst + c * 1024);
        }
        if (w < 2) {
            int c  = 4 + w;
            int nt = (c >> 1) * 16 + 2 * g + (c & 1);
            gl_lds16(srcbase + nt * 64 + lane, dst + c * 1024);
        }
    };

    // load A fragments for h-stage kt (1..16) into af[4]
    auto loadA_h = [&](int kt, bf16x8* af) {
        if (kt <= 8) {
            if (hasA) {
                const char* base = hAB + (kt - 1) * 16384 + q * 16;
#pragma unroll
                for (int mt = 0; mt < 4; mt++)
                    af[mt] = ld_frag(base + (w * 64 + mt * 16 + l16) * 64);
            } else {
#pragma unroll
                for (int mt = 0; mt < 4; mt++) af[mt] = zfrag();
            }
        } else {
            if (hasL) {
                const char* base = hLB + (kt - 9) * 16384 + q * 16;
#pragma unroll
                for (int mt = 0; mt < 4; mt++)
                    af[mt] = ld_frag(base + (w * 64 + mt * 16 + l16) * 64);
            } else {
#pragma unroll
                for (int mt = 0; mt < 4; mt++) af[mt] = zfrag();
            }
        }
    };

    auto compute = [&](const bf16x8* af, int buf, bool isX) {
        const unsigned char* bb = smemB + buf * 6144 + lane * 16;
        bf16x8 b0 = ld_frag(bb + 0 * 1024);
        bf16x8 b1 = ld_frag(bb + 1 * 1024);
        bf16x8 b2 = ld_frag(bb + 2 * 1024);
        bf16x8 b3 = ld_frag(bb + 3 * 1024);
        bf16x8 b4 = ld_frag(bb + 4 * 1024);
        bf16x8 b5 = ld_frag(bb + 5 * 1024);
        if (isX) {
#pragma unroll
            for (int mt = 0; mt < 4; mt++) {
                MFMA(af[mt], b0, acc[mt][0]); MFMA(af[mt], b1, acc[mt][1]);
                MFMA(af[mt], b2, acc[mt][2]); MFMA(af[mt], b3, acc[mt][3]);
                MFMA(af[mt], b4, acc[mt][6]); MFMA(af[mt], b5, acc[mt][7]);
            }
        } else {
#pragma unroll
            for (int mt = 0; mt < 4; mt++) {
                MFMA(af[mt], b0, acc[mt][0]); MFMA(af[mt], b1, acc[mt][1]);
                MFMA(af[mt], b2, acc[mt][2]); MFMA(af[mt], b3, acc[mt][3]);
                MFMA(af[mt], b4, acc[mt][4]); MFMA(af[mt], b5, acc[mt][5]);
            }
        }
    };

    issueB(0);

    bf16x8 afc[4], afn[4];
    // stage-0 A fragments (x patch)
    if (xpack) {
        const uint4* xpc = xpack + (size_t)((a * 29 + i) * 29 + j) * 512 + q;
#pragma unroll
        for (int mt = 0; mt < 4; mt++) {
            if (q < 2) afc[mt] = ld_frag(xpc + (w * 64 + mt * 16 + l16) * 2);
            else       afc[mt] = zfrag();
        }
    } else {
        int y0 = (a & 1) ? (27 - i) : i;
        int x0 = (a & 2) ? (27 - j) : j;
#pragma unroll
        for (int mt = 0; mt < 4; mt++) {
            if (q < 2) {
                int m = w * 64 + mt * 16 + l16;
                const float* xp = x + m * 1024 + (y0 + 2 * q) * 32 + x0;
#pragma unroll
                for (int jj = 0; jj < 8; jj++)
                    afc[mt][jj] = (__bf16)xp[(jj >> 2) * 32 + (jj & 3)];
            } else afc[mt] = zfrag();
        }
    }

    __syncthreads();                 // buf0 ready
    issueB(1);
    loadA_h(1, afn);
    compute(afc, 0, true);

    for (int kt = 1; kt <= 16; ++kt) {
        __syncthreads();             // buf[kt&1] ready
        if (kt < 16) issueB(kt + 1);
#pragma unroll
        for (int mt = 0; mt < 4; mt++) afc[mt] = afn[mt];
        if (kt < 16) loadA_h(kt + 1, afn);
        compute(afc, kt & 1, false);
    }

    // ---- epilogue: gates + state update ----
    const float* ba = bias + a * 768;
    char* houtB = (char*)(hbuf + ((size_t)(pcur * 4 + a) * 29 + j) * 65536);
#pragma unroll
    for (int s = 0; s < 2; s++) {
        int c16 = s * 16 + l16;      // c & 31
        int c = g * 32 + c16;
        float bR = ba[c], bZ = ba[256 + c], bN = ba[512 + c];
#pragma unroll
        for (int mt = 0; mt < 4; mt++) {
#pragma unroll
            for (int r2 = 0; r2 < 4; r2++) {
                int m = w * 64 + mt * 16 + q * 4 + r2;
                float rv = sigf(acc[mt][0 + s][r2] + bR);
                float zv = sigf(acc[mt][2 + s][r2] + bZ);
                float nv = tanhf_fast(acc[mt][6 + s][r2] + bN + rv * acc[mt][4 + s][r2]);
                size_t off = (size_t)g * 16384 + (size_t)m * 64 + c16 * 2;
                float hsum = 0.f;
                if (hasA) hsum += (float)(*(const __bf16*)(hAB + off));
                if (hasL) hsum += (float)(*(const __bf16*)(hLB + off));
                float hn = (1.f - zv) * nv + 0.5f * zv * hsum;
                *(__bf16*)(houtB + off) = (__bf16)hn;
            }
        }
    }
}

// ---------------------------------------------------------------------------
// Output: logits = hcat @ W_out + b_out, then log_softmax. One wave per batch.
// hbuf slice layout is k-major: elem = (c>>5)*8192 + m*32 + (c&31)
// ---------------------------------------------------------------------------
__global__ __launch_bounds__(64) void out_kernel(const __bf16* __restrict__ hbuf,
    const float* __restrict__ Wout, const float* __restrict__ bout,
    float* __restrict__ out)
{
    int b = blockIdx.x;
    int t = threadIdx.x;
    float accv[10];
#pragma unroll
    for (int o = 0; o < 10; o++) accv[o] = 0.f;
    for (int it = 0; it < 16; ++it) {
        int k = it * 64 + t;
        int a = k >> 8, c = k & 255;
        int Ny = 29 - (a & 1), Nx = 29 - ((a >> 1) & 1);
        int p  = (Ny + Nx - 2) & 1;
        int jf = Nx - 1;
        float h = (float)hbuf[((size_t)(p * 4 + a) * 29 + jf) * 65536
                              + (size_t)(c >> 5) * 8192 + (size_t)b * 32 + (c & 31)];
        const float* wr = Wout + k * 10;
#pragma unroll
        for (int o = 0; o < 10; o++) accv[o] += h * wr[o];
    }
#pragma unroll
    for (int off = 32; off > 0; off >>= 1)
#pragma unroll
        for (int o = 0; o < 10; o++) accv[o] += __shfl_down(accv[o], off, 64);
    if (t == 0) {
        float l[10];
#pragma unroll
        for (int o = 0; o < 10; o++) l[o] = accv[o] + bout[o];
        float mx = l[0];
#pragma unroll
        for (int o = 1; o < 10; o++) mx = fmaxf(mx, l[o]);
        float se = 0.f;
#pragma unroll
        for (int o = 0; o < 10; o++) se += __expf(l[o] - mx);
        float lse = mx + __logf(se);
#pragma unroll
        for (int o = 0; o < 10; o++) out[b * 10 + o] = l[o] - lse;
    }
}

extern "C" void kernel_launch(void* const* d_in, const int* in_sizes, int n_in,
                              void* d_out, int out_size, void* d_ws, size_t ws_size,
                              hipStream_t stream) {
    const float* x    = (const float*)d_in[0];
    const float* Wx   = (const float*)d_in[1];
    const float* Uh   = (const float*)d_in[2];
    const float* Uh2  = (const float*)d_in[3];
    const float* b    = (const float*)d_in[4];
    const float* Wout = (const float*)d_in[5];
    const float* bout = (const float*)d_in[6];
    float* out = (float*)d_out;

    char* ws = (char*)d_ws;
    const size_t XPACK_OFF = 3407872;
    const size_t HBUF_OFF_BIG = 31457280;
    const size_t NEED = HBUF_OFF_BIG + 30408704;
    bool use_xp = (ws_size >= NEED);

    uint4*  packW = (uint4*)ws;
    uint4*  xpack = use_xp ? (uint4*)(ws + XPACK_OFF) : nullptr;
    __bf16* hbuf  = (__bf16*)(ws + (use_xp ? HBUF_OFF_BIG : XPACK_OFF));

    pack_kernel<<<816, 256, 0, stream>>>(Wx, Uh, Uh2, packW);
    if (use_xp)
        xpack_kernel<<<6728, 256, 0, stream>>>(x, xpack);

    for (int d = 0; d < 57; ++d) {
        int cnt[4]; int maxc = 0;
        for (int a = 0; a < 4; a++) {
            int Ny = 29 - (a & 1), Nx = 29 - ((a >> 1) & 1);
            int c = 0;
            if (d <= Ny + Nx - 2) {
                int is = d - (Nx - 1); if (is < 0) is = 0;
                int ie = (d < Ny - 1) ? d : Ny - 1;
                c = ie - is + 1;
            }
            cnt[a] = c;
            if (c > maxc) maxc = c;
        }
        int grid = 64 * ((maxc + 1) >> 1);
        wf_kernel<<<grid, 256, 0, stream>>>(x, xpack, packW, b, hbuf, d,
                                            make_int4(cnt[0], cnt[1], cnt[2], cnt[3]));
    }
    out_kernel<<<256, 64, 0, stream>>>(hbuf, Wout, bout, out);
}